// Round 1
// baseline (722.214 us; speedup 1.0000x reference)
//
#include <hip/hip_runtime.h>
#include <cstdint>

// Problem constants
#define B_  4
#define T_  2048
#define D_  1024
#define H_  16
#define DH_ 64
#define R_  8
#define M_  (B_*T_)          // 8192
#define LORA_SCALE 4.0f

typedef __attribute__((ext_vector_type(8))) short    bf16x8;
typedef __attribute__((ext_vector_type(4))) float    f32x4;
typedef __attribute__((ext_vector_type(4))) uint32_t u32x4;

__device__ inline uint16_t f2b(float f) {             // fp32 -> bf16 RNE
    uint32_t x = __float_as_uint(f);
    return (uint16_t)((x + 0x7fffu + ((x >> 16) & 1u)) >> 16);
}
__device__ inline float b2f(uint16_t u) { return __uint_as_float(((uint32_t)u) << 16); }

// ---------------------------------------------------------------------------
// K1: cast query fp32 -> bf16   (8 elems/thread)
// ---------------------------------------------------------------------------
__global__ void cast_x_kernel(const float* __restrict__ x, uint16_t* __restrict__ out) {
    int g = blockIdx.x * 256 + threadIdx.x;            // 1M threads, 8M elems
    const float4* xv = (const float4*)x;
    float4 a = xv[2 * g], b = xv[2 * g + 1];
    union { u32x4 v; uint16_t s[8]; } u;
    u.s[0] = f2b(a.x); u.s[1] = f2b(a.y); u.s[2] = f2b(a.z); u.s[3] = f2b(a.w);
    u.s[4] = f2b(b.x); u.s[5] = f2b(b.y); u.s[6] = f2b(b.z); u.s[7] = f2b(b.w);
    ((u32x4*)out)[g] = u.v;
}

// ---------------------------------------------------------------------------
// K2: build transposed bf16 weights Wt[n][k]; fold LoRA into wq/wv.
// LDS 64x64 tile transpose: coalesced reads AND writes.
// grid (16 ntiles, 16 ktiles, 4 mats), 256 thr
// ---------------------------------------------------------------------------
__global__ void make_wt_kernel(const float* __restrict__ wq, const float* __restrict__ wk,
                               const float* __restrict__ wv, const float* __restrict__ wo,
                               const float* __restrict__ Aq, const float* __restrict__ Bq,
                               const float* __restrict__ Av, const float* __restrict__ Bv,
                               uint16_t* __restrict__ Wt) {
    __shared__ float tile[64][65];
    int mat = blockIdx.z;
    int n0 = blockIdx.x * 64, k0 = blockIdx.y * 64;
    const float* W  = (mat == 0) ? wq : (mat == 1) ? wk : (mat == 2) ? wv : wo;
    const float* Ap = (mat == 0) ? Aq : (mat == 2) ? Av : nullptr;
    const float* Bp = (mat == 0) ? Bq : (mat == 2) ? Bv : nullptr;
    int t = threadIdx.x;
    int r = t >> 2, c0 = (t & 3) * 16;                 // read: row k0+r, 16 consecutive n
    int k = k0 + r;
    #pragma unroll
    for (int j = 0; j < 16; j++) {
        int n = n0 + c0 + j;
        float v = W[(size_t)k * D_ + n];
        if (Ap) {
            float acc = 0.f;
            #pragma unroll
            for (int rr = 0; rr < R_; rr++) acc += Ap[k * R_ + rr] * Bp[rr * D_ + n];
            v += LORA_SCALE * acc;
        }
        tile[r][c0 + j] = v;
    }
    __syncthreads();
    int nl = t >> 2, ks = (t & 3) * 16;                // write: row n0+nl, 16 consecutive k
    union { uint16_t s[16]; u32x4 v[2]; } uo;
    #pragma unroll
    for (int j = 0; j < 16; j++) uo.s[j] = f2b(tile[ks + j][nl]);
    uint16_t* dst = Wt + (size_t)mat * D_ * D_ + (size_t)(n0 + nl) * D_ + k0 + ks;
    *(u32x4*)&dst[0] = uo.v[0];
    *(u32x4*)&dst[8] = uo.v[1];
}

// ---------------------------------------------------------------------------
// K3/K7: C = A(MxK bf16, row-major) @ Bt(NxK bf16, row-major)^T
// 128x128 block tile, 4 waves (2x2), each wave 4x4 MFMA 16x16x32 tiles, BK=32.
// ---------------------------------------------------------------------------
template <bool OUT_F32>
__global__ __launch_bounds__(256)
void gemm_bt_kernel(const uint16_t* __restrict__ A, const uint16_t* __restrict__ Bt,
                    uint16_t* __restrict__ Cb, float* __restrict__ Cf,
                    int Mdim, int Ndim, int Kdim) {
    __shared__ uint16_t At[128 * 32];
    __shared__ uint16_t Bs[128 * 32];
    int tid = threadIdx.x;
    int wave = tid >> 6, lane = tid & 63, quad = lane >> 4, l15 = lane & 15;
    int rowBase = blockIdx.y * 128, colBase = blockIdx.x * 128;
    int wRow = (wave >> 1) * 64, wCol = (wave & 1) * 64;
    f32x4 acc[4][4] = {};
    for (int kb = 0; kb < Kdim; kb += 32) {
        #pragma unroll
        for (int i = 0; i < 2; i++) {
            int c = tid + i * 256;                     // 512 16B chunks per tile
            int row = c >> 2, seg = c & 3;
            *(u32x4*)&At[row * 32 + seg * 8] =
                *(const u32x4*)&A[(size_t)(rowBase + row) * Kdim + kb + seg * 8];
            *(u32x4*)&Bs[row * 32 + seg * 8] =
                *(const u32x4*)&Bt[(size_t)(colBase + row) * Kdim + kb + seg * 8];
        }
        __syncthreads();
        bf16x8 af[4], bfr[4];
        #pragma unroll
        for (int m = 0; m < 4; m++) af[m]  = *(const bf16x8*)&At[(wRow + m * 16 + l15) * 32 + quad * 8];
        #pragma unroll
        for (int n = 0; n < 4; n++) bfr[n] = *(const bf16x8*)&Bs[(wCol + n * 16 + l15) * 32 + quad * 8];
        #pragma unroll
        for (int m = 0; m < 4; m++)
            #pragma unroll
            for (int n = 0; n < 4; n++)
                acc[m][n] = __builtin_amdgcn_mfma_f32_16x16x32_bf16(af[m], bfr[n], acc[m][n], 0, 0, 0);
        __syncthreads();
    }
    #pragma unroll
    for (int m = 0; m < 4; m++) {
        int row = rowBase + wRow + m * 16 + quad * 4;  // C/D: row = quad*4+reg
        #pragma unroll
        for (int n = 0; n < 4; n++) {
            int col = colBase + wCol + n * 16 + l15;   // C/D: col = lane&15
            #pragma unroll
            for (int r = 0; r < 4; r++) {
                float v = acc[m][n][r];
                if (OUT_F32) Cf[(size_t)(row + r) * Ndim + col] = v;
                else         Cb[(size_t)(row + r) * Ndim + col] = f2b(v);
            }
        }
    }
}

// ---------------------------------------------------------------------------
// K4: RoPE on q,k; reshape (B,T,3D) -> (B,H,T,dh). One thread per (b,h,t,pair).
// ---------------------------------------------------------------------------
__global__ void rope_kernel(const uint16_t* __restrict__ qkv,
                            uint16_t* __restrict__ Qr, uint16_t* __restrict__ Kr) {
    int g = blockIdx.x * 256 + threadIdx.x;            // 4M = B*H*T*32
    int i  = g & 31;                                   // pair index (dims 2i, 2i+1)
    int t  = (g >> 5) & (T_ - 1);
    int bh = g >> 16;
    int h = bh & 15, b = bh >> 4;
    size_t rowoff = ((size_t)(b * T_ + t)) * 3072 + h * 64 + 2 * i;
    uint32_t qp = *(const uint32_t*)&qkv[rowoff];
    uint32_t kp = *(const uint32_t*)&qkv[rowoff + 1024];
    float qe = b2f((uint16_t)qp), qo = b2f((uint16_t)(qp >> 16));
    float ke = b2f((uint16_t)kp), ko = b2f((uint16_t)(kp >> 16));
    // theta = t / 10000^(i/32);  log2(10000) = 13.287712379549449
    float inv = exp2f(-(float)i * (13.2877123795494f / 32.f));
    float th = (float)t * inv;
    float s = sinf(th), c = cosf(th);
    uint32_t qw = (uint32_t)f2b(qe * c - qo * s) | ((uint32_t)f2b(qe * s + qo * c) << 16);
    uint32_t kw = (uint32_t)f2b(ke * c - ko * s) | ((uint32_t)f2b(ke * s + ko * c) << 16);
    size_t o = ((size_t)bh * T_ + t) * 64 + 2 * i;
    *(uint32_t*)&Qr[o] = qw;
    *(uint32_t*)&Kr[o] = kw;
}

// ---------------------------------------------------------------------------
// K5: V -> Vt (B,H,dh,T) via LDS tile transpose. grid (T/32, B*H), 256 thr.
// ---------------------------------------------------------------------------
__global__ void vtrans_kernel(const uint16_t* __restrict__ qkv, uint16_t* __restrict__ Vt) {
    __shared__ uint16_t tile[32][72];
    int bh = blockIdx.y, t0 = blockIdx.x * 32;
    int b = bh >> 4, h = bh & 15;
    int tid = threadIdx.x;
    int r = tid >> 3, c8 = (tid & 7) * 8;              // read 32 t-rows x 64 d, 8 elems/thr
    *(u32x4*)&tile[r][c8] =
        *(const u32x4*)&qkv[((size_t)(b * T_ + t0 + r)) * 3072 + 2048 + h * 64 + c8];
    __syncthreads();
    int d = tid >> 2, t8 = (tid & 3) * 8;              // write 64 d-rows x 32 t
    union { uint16_t s[8]; u32x4 v; } uu;
    #pragma unroll
    for (int j = 0; j < 8; j++) uu.s[j] = tile[t8 + j][d];
    *(u32x4*)&Vt[((size_t)bh * 64 + d) * T_ + t0 + t8] = uu.v;
}

// ---------------------------------------------------------------------------
// K6: causal flash attention. grid (T/64 qtiles, B*H), 256 thr = 4 waves.
// Wave w owns q rows [qt*64 + w*16, +16); loops k-tiles of 64, online softmax.
// Q,K read direct from global in MFMA A/B layout; V read from Vt (pre-transposed).
// P goes C-layout -> A-layout through a private per-wave LDS slab (no barriers).
// ---------------------------------------------------------------------------
__global__ __launch_bounds__(256)
void attn_kernel(const uint16_t* __restrict__ Qr, const uint16_t* __restrict__ Kr,
                 const uint16_t* __restrict__ Vt, uint16_t* __restrict__ Obuf) {
    __shared__ uint16_t Pl[4][16][64];
    int qt = blockIdx.x, bh = blockIdx.y;
    int b = bh >> 4, h = bh & 15;
    int tid = threadIdx.x, wave = tid >> 6, lane = tid & 63, quad = lane >> 4, l15 = lane & 15;
    int q0 = qt * 64 + wave * 16;
    const uint16_t* Qbase = Qr + ((size_t)bh * T_) * 64;
    const uint16_t* Kbase = Kr + ((size_t)bh * T_) * 64;
    const uint16_t* Vbase = Vt + ((size_t)bh * 64) * T_;
    bf16x8 aQ[2];
    aQ[0] = *(const bf16x8*)&Qbase[(q0 + l15) * 64 + quad * 8];        // A: m=l15, k=quad*8+j
    aQ[1] = *(const bf16x8*)&Qbase[(q0 + l15) * 64 + 32 + quad * 8];
    f32x4 Oacc[4] = {};
    float mrow[4] = {-1e30f, -1e30f, -1e30f, -1e30f};
    float lrow[4] = {0.f, 0.f, 0.f, 0.f};
    for (int kt = 0; kt <= qt; kt++) {
        int k0 = kt * 64;
        f32x4 sacc[4] = {};
        #pragma unroll
        for (int s = 0; s < 2; s++) {
            #pragma unroll
            for (int n = 0; n < 4; n++) {
                bf16x8 bK = *(const bf16x8*)&Kbase[(k0 + n * 16 + l15) * 64 + s * 32 + quad * 8];
                sacc[n] = __builtin_amdgcn_mfma_f32_16x16x32_bf16(aQ[s], bK, sacc[n], 0, 0, 0);
            }
        }
        bool diag = (kt == qt);
        float p[4][4];
        #pragma unroll
        for (int r = 0; r < 4; r++) {
            int qg = q0 + quad * 4 + r;                 // D: row = quad*4+reg
            float mx = -1e30f;
            #pragma unroll
            for (int n = 0; n < 4; n++) {
                float v = sacc[n][r] * 0.125f;          // 1/sqrt(64)
                if (diag && (k0 + n * 16 + l15) > qg) v = -1e30f;   // causal: k > q
                p[n][r] = v;
                mx = fmaxf(mx, v);
            }
            #pragma unroll
            for (int m = 1; m < 16; m <<= 1) mx = fmaxf(mx, __shfl_xor(mx, m, 64));
            float mnew = fmaxf(mrow[r], mx);
            float alpha = __expf(mrow[r] - mnew);
            float sum = 0.f;
            #pragma unroll
            for (int n = 0; n < 4; n++) { float e = __expf(p[n][r] - mnew); p[n][r] = e; sum += e; }
            #pragma unroll
            for (int m = 1; m < 16; m <<= 1) sum += __shfl_xor(sum, m, 64);
            lrow[r] = lrow[r] * alpha + sum;
            mrow[r] = mnew;
            #pragma unroll
            for (int n = 0; n < 4; n++) Oacc[n][r] *= alpha;
        }
        #pragma unroll
        for (int r = 0; r < 4; r++)
            #pragma unroll
            for (int n = 0; n < 4; n++)
                Pl[wave][quad * 4 + r][n * 16 + l15] = f2b(p[n][r]);   // C-layout store
        #pragma unroll
        for (int s = 0; s < 2; s++) {
            bf16x8 aP = *(const bf16x8*)&Pl[wave][l15][s * 32 + quad * 8];  // A-layout read
            #pragma unroll
            for (int n = 0; n < 4; n++) {
                bf16x8 bV = *(const bf16x8*)&Vbase[(n * 16 + l15) * T_ + k0 + s * 32 + quad * 8];
                Oacc[n] = __builtin_amdgcn_mfma_f32_16x16x32_bf16(aP, bV, Oacc[n], 0, 0, 0);
            }
        }
    }
    #pragma unroll
    for (int n = 0; n < 4; n++) {
        #pragma unroll
        for (int r = 0; r < 4; r++) {
            int qg = q0 + quad * 4 + r;
            float v = Oacc[n][r] / lrow[r];
            Obuf[((size_t)(b * T_ + qg)) * D_ + h * 64 + n * 16 + l15] = f2b(v);
        }
    }
}

// ---------------------------------------------------------------------------
extern "C" void kernel_launch(void* const* d_in, const int* in_sizes, int n_in,
                              void* d_out, int out_size, void* d_ws, size_t ws_size,
                              hipStream_t stream) {
    const float* query = (const float*)d_in[0];
    const float* wq = (const float*)d_in[1];
    const float* wk = (const float*)d_in[2];
    const float* wv = (const float*)d_in[3];
    const float* wo = (const float*)d_in[4];
    const float* Aq = (const float*)d_in[5];
    const float* Bq = (const float*)d_in[6];
    const float* Av = (const float*)d_in[7];
    const float* Bv = (const float*)d_in[8];
    float* out = (float*)d_out;

    const size_t MB = 1ull << 20;
    if (ws_size < 120 * MB) return;                    // need 120 MB scratch
    char* ws = (char*)d_ws;
    uint16_t* Xbf = (uint16_t*)(ws);                   // 16 MB  (8192x1024 bf16)
    uint16_t* Wt  = (uint16_t*)(ws + 16 * MB);         //  8 MB  (4x 1024x1024 bf16, N-major)
    uint16_t* qkv = (uint16_t*)(ws + 24 * MB);         // 48 MB  (8192x3072 bf16)
    uint16_t* Qr  = (uint16_t*)(ws + 72 * MB);         // 16 MB  (B,H,T,dh)
    uint16_t* Kr  = (uint16_t*)(ws + 88 * MB);         // 16 MB
    uint16_t* Vt  = (uint16_t*)(ws + 104 * MB);        // 16 MB  (B,H,dh,T)
    uint16_t* Obuf = qkv;                              // reuse qkv region (dead after rope/vtrans)

    cast_x_kernel<<<4096, 256, 0, stream>>>(query, Xbf);
    make_wt_kernel<<<dim3(16, 16, 4), 256, 0, stream>>>(wq, wk, wv, wo, Aq, Bq, Av, Bv, Wt);
    // fused QKV projection: Bt rows 0..3071 = [Wq_eff | Wk | Wv_eff]
    gemm_bt_kernel<false><<<dim3(3072 / 128, M_ / 128), 256, 0, stream>>>(
        Xbf, Wt, qkv, nullptr, M_, 3072, D_);
    rope_kernel<<<16384, 256, 0, stream>>>(qkv, Qr, Kr);
    vtrans_kernel<<<dim3(T_ / 32, B_ * H_), 256, 0, stream>>>(qkv, Vt);
    attn_kernel<<<dim3(T_ / 64, B_ * H_), 256, 0, stream>>>(Qr, Kr, Vt, Obuf);
    gemm_bt_kernel<true><<<dim3(D_ / 128, M_ / 128), 256, 0, stream>>>(
        Obuf, Wt + 3ull * D_ * D_, nullptr, out, M_, D_, D_);
}

// Round 2
// 472.484 us; speedup vs baseline: 1.5285x; 1.5285x over previous
//
#include <hip/hip_runtime.h>
#include <cstdint>

// Problem constants
#define B_  4
#define T_  2048
#define D_  1024
#define H_  16
#define DH_ 64
#define R_  8
#define M_  (B_*T_)          // 8192
#define LORA_SCALE 4.0f

typedef __attribute__((ext_vector_type(8))) short    bf16x8;
typedef __attribute__((ext_vector_type(4))) short    bf16x4;
typedef __attribute__((ext_vector_type(4))) float    f32x4;
typedef __attribute__((ext_vector_type(4))) uint32_t u32x4;

__device__ inline uint16_t f2b(float f) {             // fp32 -> bf16 RNE
    uint32_t x = __float_as_uint(f);
    return (uint16_t)((x + 0x7fffu + ((x >> 16) & 1u)) >> 16);
}
__device__ inline float b2f(uint16_t u) { return __uint_as_float(((uint32_t)u) << 16); }

// ---------------------------------------------------------------------------
// K1: cast query fp32 -> bf16   (8 elems/thread)
// ---------------------------------------------------------------------------
__global__ void cast_x_kernel(const float* __restrict__ x, uint16_t* __restrict__ out) {
    int g = blockIdx.x * 256 + threadIdx.x;
    const float4* xv = (const float4*)x;
    float4 a = xv[2 * g], b = xv[2 * g + 1];
    union { u32x4 v; uint16_t s[8]; } u;
    u.s[0] = f2b(a.x); u.s[1] = f2b(a.y); u.s[2] = f2b(a.z); u.s[3] = f2b(a.w);
    u.s[4] = f2b(b.x); u.s[5] = f2b(b.y); u.s[6] = f2b(b.z); u.s[7] = f2b(b.w);
    ((u32x4*)out)[g] = u.v;
}

// ---------------------------------------------------------------------------
// K2: build transposed bf16 weights Wt[n][k]; fold LoRA into wq/wv.
// ---------------------------------------------------------------------------
__global__ void make_wt_kernel(const float* __restrict__ wq, const float* __restrict__ wk,
                               const float* __restrict__ wv, const float* __restrict__ wo,
                               const float* __restrict__ Aq, const float* __restrict__ Bq,
                               const float* __restrict__ Av, const float* __restrict__ Bv,
                               uint16_t* __restrict__ Wt) {
    __shared__ float tile[64][65];
    int mat = blockIdx.z;
    int n0 = blockIdx.x * 64, k0 = blockIdx.y * 64;
    const float* W  = (mat == 0) ? wq : (mat == 1) ? wk : (mat == 2) ? wv : wo;
    const float* Ap = (mat == 0) ? Aq : (mat == 2) ? Av : nullptr;
    const float* Bp = (mat == 0) ? Bq : (mat == 2) ? Bv : nullptr;
    int t = threadIdx.x;
    int r = t >> 2, c0 = (t & 3) * 16;
    int k = k0 + r;
    #pragma unroll
    for (int j = 0; j < 16; j++) {
        int n = n0 + c0 + j;
        float v = W[(size_t)k * D_ + n];
        if (Ap) {
            float acc = 0.f;
            #pragma unroll
            for (int rr = 0; rr < R_; rr++) acc += Ap[k * R_ + rr] * Bp[rr * D_ + n];
            v += LORA_SCALE * acc;
        }
        tile[r][c0 + j] = v;
    }
    __syncthreads();
    int nl = t >> 2, ks = (t & 3) * 16;
    union { uint16_t s[16]; u32x4 v[2]; } uo;
    #pragma unroll
    for (int j = 0; j < 16; j++) uo.s[j] = f2b(tile[ks + j][nl]);
    uint16_t* dst = Wt + (size_t)mat * D_ * D_ + (size_t)(n0 + nl) * D_ + k0 + ks;
    *(u32x4*)&dst[0] = uo.v[0];
    *(u32x4*)&dst[8] = uo.v[1];
}

// ---------------------------------------------------------------------------
// K3/K7: C = A(MxK bf16, row-major) @ Bt(NxK bf16, row-major)^T
// ---------------------------------------------------------------------------
template <bool OUT_F32>
__global__ __launch_bounds__(256)
void gemm_bt_kernel(const uint16_t* __restrict__ A, const uint16_t* __restrict__ Bt,
                    uint16_t* __restrict__ Cb, float* __restrict__ Cf,
                    int Mdim, int Ndim, int Kdim) {
    __shared__ uint16_t At[128 * 32];
    __shared__ uint16_t Bs[128 * 32];
    int tid = threadIdx.x;
    int wave = tid >> 6, lane = tid & 63, quad = lane >> 4, l15 = lane & 15;
    int rowBase = blockIdx.y * 128, colBase = blockIdx.x * 128;
    int wRow = (wave >> 1) * 64, wCol = (wave & 1) * 64;
    f32x4 acc[4][4] = {};
    for (int kb = 0; kb < Kdim; kb += 32) {
        #pragma unroll
        for (int i = 0; i < 2; i++) {
            int c = tid + i * 256;
            int row = c >> 2, seg = c & 3;
            *(u32x4*)&At[row * 32 + seg * 8] =
                *(const u32x4*)&A[(size_t)(rowBase + row) * Kdim + kb + seg * 8];
            *(u32x4*)&Bs[row * 32 + seg * 8] =
                *(const u32x4*)&Bt[(size_t)(colBase + row) * Kdim + kb + seg * 8];
        }
        __syncthreads();
        bf16x8 af[4], bfr[4];
        #pragma unroll
        for (int m = 0; m < 4; m++) af[m]  = *(const bf16x8*)&At[(wRow + m * 16 + l15) * 32 + quad * 8];
        #pragma unroll
        for (int n = 0; n < 4; n++) bfr[n] = *(const bf16x8*)&Bs[(wCol + n * 16 + l15) * 32 + quad * 8];
        #pragma unroll
        for (int m = 0; m < 4; m++)
            #pragma unroll
            for (int n = 0; n < 4; n++)
                acc[m][n] = __builtin_amdgcn_mfma_f32_16x16x32_bf16(af[m], bfr[n], acc[m][n], 0, 0, 0);
        __syncthreads();
    }
    #pragma unroll
    for (int m = 0; m < 4; m++) {
        int row = rowBase + wRow + m * 16 + quad * 4;
        #pragma unroll
        for (int n = 0; n < 4; n++) {
            int col = colBase + wCol + n * 16 + l15;
            #pragma unroll
            for (int r = 0; r < 4; r++) {
                float v = acc[m][n][r];
                if (OUT_F32) Cf[(size_t)(row + r) * Ndim + col] = v;
                else         Cb[(size_t)(row + r) * Ndim + col] = f2b(v);
            }
        }
    }
}

// ---------------------------------------------------------------------------
// K4: RoPE on q,k; reshape (B,T,3D) -> (B,H,T,dh).
// ---------------------------------------------------------------------------
__global__ void rope_kernel(const uint16_t* __restrict__ qkv,
                            uint16_t* __restrict__ Qr, uint16_t* __restrict__ Kr) {
    int g = blockIdx.x * 256 + threadIdx.x;
    int i  = g & 31;
    int t  = (g >> 5) & (T_ - 1);
    int bh = g >> 16;
    int h = bh & 15, b = bh >> 4;
    size_t rowoff = ((size_t)(b * T_ + t)) * 3072 + h * 64 + 2 * i;
    uint32_t qp = *(const uint32_t*)&qkv[rowoff];
    uint32_t kp = *(const uint32_t*)&qkv[rowoff + 1024];
    float qe = b2f((uint16_t)qp), qo = b2f((uint16_t)(qp >> 16));
    float ke = b2f((uint16_t)kp), ko = b2f((uint16_t)(kp >> 16));
    float inv = exp2f(-(float)i * (13.2877123795494f / 32.f));
    float th = (float)t * inv;
    float s = sinf(th), c = cosf(th);
    uint32_t qw = (uint32_t)f2b(qe * c - qo * s) | ((uint32_t)f2b(qe * s + qo * c) << 16);
    uint32_t kw = (uint32_t)f2b(ke * c - ko * s) | ((uint32_t)f2b(ke * s + ko * c) << 16);
    size_t o = ((size_t)bh * T_ + t) * 64 + 2 * i;
    *(uint32_t*)&Qr[o] = qw;
    *(uint32_t*)&Kr[o] = kw;
}

// ---------------------------------------------------------------------------
// K5: V -> Vt (B,H,dh,T) via LDS tile transpose.
// ---------------------------------------------------------------------------
__global__ void vtrans_kernel(const uint16_t* __restrict__ qkv, uint16_t* __restrict__ Vt) {
    __shared__ uint16_t tile[32][72];
    int bh = blockIdx.y, t0 = blockIdx.x * 32;
    int b = bh >> 4, h = bh & 15;
    int tid = threadIdx.x;
    int r = tid >> 3, c8 = (tid & 7) * 8;
    *(u32x4*)&tile[r][c8] =
        *(const u32x4*)&qkv[((size_t)(b * T_ + t0 + r)) * 3072 + 2048 + h * 64 + c8];
    __syncthreads();
    int d = tid >> 2, t8 = (tid & 3) * 8;
    union { uint16_t s[8]; u32x4 v; } uu;
    #pragma unroll
    for (int j = 0; j < 8; j++) uu.s[j] = tile[t8 + j][d];
    *(u32x4*)&Vt[((size_t)bh * 64 + d) * T_ + t0 + t8] = uu.v;
}

// ---------------------------------------------------------------------------
// K6: causal flash attention, S^T orientation.
// grid (16, B*H): block x handles q-tiles {x, 31-x} (balanced: 9 chunks each).
// 4 independent waves; wave owns 16 q rows. k-chunks of 256.
// S^T = K.Q^T  => lane owns one q-column (q=lane&15): softmax reduce = 2 shfl.
// P^T C-layout packs 4 consecutive kpos per lane -> ds_write_b64.
// O^T = V^T.P^T with V^T read straight from Vt.
// ---------------------------------------------------------------------------
#define PSTRIDE 264   // bf16 elems per P row: 528B, 16B-aligned, bank-spread

template <bool MASKED>
__device__ __forceinline__ void attn_chunk(
    const uint16_t* __restrict__ Kb, const uint16_t* __restrict__ Vb,
    uint16_t* __restrict__ Pw, int k0, int nact, int base_kmq,
    bf16x8 aQ0, bf16x8 aQ1, int l15, int quad,
    f32x4 (&Oacc)[4], float& mrow, float& lrow)
{
    f32x4 sacc[16];
    #pragma unroll
    for (int n = 0; n < 16; n++) {
        if (MASKED && n >= nact) continue;
        const uint16_t* kr = &Kb[(size_t)(k0 + n * 16 + l15) * 64 + quad * 8];
        bf16x8 kv0 = *(const bf16x8*)kr;
        bf16x8 kv1 = *(const bf16x8*)(kr + 32);
        f32x4 s = {};
        s = __builtin_amdgcn_mfma_f32_16x16x32_bf16(kv0, aQ0, s, 0, 0, 0);
        s = __builtin_amdgcn_mfma_f32_16x16x32_bf16(kv1, aQ1, s, 0, 0, 0);
        sacc[n] = s;
    }
    const float SC = 0.125f * 1.44269504089f;   // scale * log2(e)
    float mx = -1e30f;
    #pragma unroll
    for (int n = 0; n < 16; n++) {
        if (MASKED && n >= nact) continue;
        #pragma unroll
        for (int r = 0; r < 4; r++) {
            float v = sacc[n][r] * SC;
            if (MASKED) {
                int kmq = base_kmq + n * 16 + quad * 4 + r;   // kpos - q
                v = (kmq > 0) ? -1e30f : v;
            }
            sacc[n][r] = v;
            mx = fmaxf(mx, v);
        }
    }
    mx = fmaxf(mx, __shfl_xor(mx, 16, 64));
    mx = fmaxf(mx, __shfl_xor(mx, 32, 64));
    float mnew = fmaxf(mrow, mx);
    float alpha = exp2f(mrow - mnew);
    float sum = 0.f;
    #pragma unroll
    for (int n = 0; n < 16; n++) {
        if (MASKED && n >= nact) continue;
        #pragma unroll
        for (int r = 0; r < 4; r++) {
            float e = exp2f(sacc[n][r] - mnew);
            sacc[n][r] = e;
            sum += e;
        }
    }
    sum += __shfl_xor(sum, 16, 64);
    sum += __shfl_xor(sum, 32, 64);
    lrow = lrow * alpha + sum;
    mrow = mnew;
    #pragma unroll
    for (int m = 0; m < 4; m++)
        #pragma unroll
        for (int r = 0; r < 4; r++) Oacc[m][r] *= alpha;
    // P^T -> LDS: row q=l15, 4 consecutive kpos per lane -> b64
    #pragma unroll
    for (int n = 0; n < 16; n++) {
        if (MASKED && n >= nact) continue;
        bf16x4 pk;
        pk[0] = (short)f2b(sacc[n][0]); pk[1] = (short)f2b(sacc[n][1]);
        pk[2] = (short)f2b(sacc[n][2]); pk[3] = (short)f2b(sacc[n][3]);
        *(bf16x4*)&Pw[l15 * PSTRIDE + n * 16 + quad * 4] = pk;
    }
    if (MASKED && (nact & 1)) {                 // zero odd tail tile for PV b128 reads
        bf16x4 z = {};
        *(bf16x4*)&Pw[l15 * PSTRIDE + nact * 16 + quad * 4] = z;
    }
    int ssact = MASKED ? ((nact + 1) >> 1) : 8;
    #pragma unroll
    for (int ss = 0; ss < 8; ss++) {
        if (MASKED && ss >= ssact) continue;
        bf16x8 bP = *(const bf16x8*)&Pw[l15 * PSTRIDE + ss * 32 + quad * 8];
        #pragma unroll
        for (int m = 0; m < 4; m++) {
            bf16x8 aV = *(const bf16x8*)&Vb[(size_t)(m * 16 + l15) * T_ + k0 + ss * 32 + quad * 8];
            Oacc[m] = __builtin_amdgcn_mfma_f32_16x16x32_bf16(aV, bP, Oacc[m], 0, 0, 0);
        }
    }
}

__global__ __launch_bounds__(256, 4)
void attn_kernel(const uint16_t* __restrict__ Qr, const uint16_t* __restrict__ Kr,
                 const uint16_t* __restrict__ Vt, uint16_t* __restrict__ Obuf) {
    __shared__ uint16_t Pl[4][16 * PSTRIDE];    // 33792 B
    int bh = blockIdx.y;
    int b = bh >> 4, h = bh & 15;
    int tid = threadIdx.x, wave = tid >> 6, lane = tid & 63, quad = lane >> 4, l15 = lane & 15;
    const uint16_t* Qbase = Qr + (size_t)bh * T_ * 64;
    const uint16_t* Kbase = Kr + (size_t)bh * T_ * 64;
    const uint16_t* Vbase = Vt + (size_t)bh * 64 * T_;
    uint16_t* Pw = &Pl[wave][0];
    #pragma unroll
    for (int pass = 0; pass < 2; pass++) {
        int qt = pass ? (31 - (int)blockIdx.x) : (int)blockIdx.x;
        int q0w = qt * 64 + wave * 16;
        bf16x8 aQ0 = *(const bf16x8*)&Qbase[(size_t)(q0w + l15) * 64 + quad * 8];
        bf16x8 aQ1 = *(const bf16x8*)&Qbase[(size_t)(q0w + l15) * 64 + 32 + quad * 8];
        f32x4 Oacc[4] = {};
        float mrow = -1e30f, lrow = 0.f;
        int niter = (qt >> 2) + 1;
        int klim = q0w + 15;
        for (int it = 0; it < niter - 1; it++)
            attn_chunk<false>(Kbase, Vbase, Pw, it * 256, 16, 0,
                              aQ0, aQ1, l15, quad, Oacc, mrow, lrow);
        {
            int k0 = (niter - 1) * 256;
            int nact = ((klim - k0) >> 4) + 1;
            attn_chunk<true>(Kbase, Vbase, Pw, k0, nact, k0 - q0w - l15,
                             aQ0, aQ1, l15, quad, Oacc, mrow, lrow);
        }
        // epilogue: O^T (row=dh=m*16+quad*4+r, col=q=l15) -> LDS -> coalesced global
        float invl = 1.0f / lrow;
        float* Ow = (float*)Pw;                 // 16 q-rows x 68 f32 (272B stride)
        #pragma unroll
        for (int m = 0; m < 4; m++) {
            f32x4 o;
            #pragma unroll
            for (int r = 0; r < 4; r++) o[r] = Oacc[m][r] * invl;
            *(f32x4*)&Ow[l15 * 68 + m * 16 + quad * 4] = o;
        }
        int orow = lane >> 2, ocol = (lane & 3) * 16;
        #pragma unroll
        for (int jj = 0; jj < 4; jj++) {
            f32x4 ov = *(const f32x4*)&Ow[orow * 68 + ocol + jj * 4];
            bf16x4 ob;
            ob[0] = (short)f2b(ov[0]); ob[1] = (short)f2b(ov[1]);
            ob[2] = (short)f2b(ov[2]); ob[3] = (short)f2b(ov[3]);
            *(bf16x4*)&Obuf[((size_t)(b * T_ + qt * 64 + wave * 16 + orow)) * D_
                            + h * 64 + ocol + jj * 4] = ob;
        }
    }
}

// ---------------------------------------------------------------------------
extern "C" void kernel_launch(void* const* d_in, const int* in_sizes, int n_in,
                              void* d_out, int out_size, void* d_ws, size_t ws_size,
                              hipStream_t stream) {
    const float* query = (const float*)d_in[0];
    const float* wq = (const float*)d_in[1];
    const float* wk = (const float*)d_in[2];
    const float* wv = (const float*)d_in[3];
    const float* wo = (const float*)d_in[4];
    const float* Aq = (const float*)d_in[5];
    const float* Bq = (const float*)d_in[6];
    const float* Av = (const float*)d_in[7];
    const float* Bv = (const float*)d_in[8];
    float* out = (float*)d_out;

    const size_t MB = 1ull << 20;
    if (ws_size < 120 * MB) return;
    char* ws = (char*)d_ws;
    uint16_t* Xbf = (uint16_t*)(ws);                   // 16 MB
    uint16_t* Wt  = (uint16_t*)(ws + 16 * MB);         //  8 MB
    uint16_t* qkv = (uint16_t*)(ws + 24 * MB);         // 48 MB
    uint16_t* Qr  = (uint16_t*)(ws + 72 * MB);         // 16 MB
    uint16_t* Kr  = (uint16_t*)(ws + 88 * MB);         // 16 MB
    uint16_t* Vt  = (uint16_t*)(ws + 104 * MB);        // 16 MB
    uint16_t* Obuf = qkv;                              // reuse (dead after rope/vtrans)

    cast_x_kernel<<<4096, 256, 0, stream>>>(query, Xbf);
    make_wt_kernel<<<dim3(16, 16, 4), 256, 0, stream>>>(wq, wk, wv, wo, Aq, Bq, Av, Bv, Wt);
    gemm_bt_kernel<false><<<dim3(3072 / 128, M_ / 128), 256, 0, stream>>>(
        Xbf, Wt, qkv, nullptr, M_, 3072, D_);
    rope_kernel<<<16384, 256, 0, stream>>>(qkv, Qr, Kr);
    vtrans_kernel<<<dim3(T_ / 32, B_ * H_), 256, 0, stream>>>(qkv, Vt);
    attn_kernel<<<dim3(16, B_ * H_), 256, 0, stream>>>(Qr, Kr, Vt, Obuf);
    gemm_bt_kernel<true><<<dim3(D_ / 128, M_ / 128), 256, 0, stream>>>(
        Obuf, Wt + 3ull * D_ * D_, nullptr, out, M_, D_, D_);
}